// Round 2
// baseline (339.547 us; speedup 1.0000x reference)
//
#include <hip/hip_runtime.h>

#define HID 256
#define NFEAT 8
#define SLEN 2048

__global__ __launch_bounds__(256, 4) void stab_embed_ln_kernel(
    const float* __restrict__ x,      // [B,S,F]
    const int*   __restrict__ mask,   // [B,S]
    const float* __restrict__ W,      // [F,H]
    const float* __restrict__ bias,   // [F,H]
    const float* __restrict__ ie,     // [S,H]
    const float* __restrict__ fon,    // [H]
    const float* __restrict__ foff,   // [H]
    const float* __restrict__ gamma,  // [H]
    const float* __restrict__ beta,   // [H]
    float* __restrict__ out,          // [B,S,H]
    int ntokens)
{
    const int lane = threadIdx.x & 63;
    const int waveInBlock = threadIdx.x >> 6;
    const int wavesPerBlock = blockDim.x >> 6;
    const int gwave = blockIdx.x * wavesPerBlock + waveInBlock;
    const int nwaves = gridDim.x * wavesPerBlock;

    const int h0 = lane << 2;  // 4 consecutive h per lane

    // ---- per-lane loop invariants (tables are tiny, L1/L2-resident) ----
    float wc[NFEAT][4];
#pragma unroll
    for (int f = 0; f < NFEAT; ++f) {
        const float4 w4 = *reinterpret_cast<const float4*>(W + f * HID + h0);
        wc[f][0] = w4.x; wc[f][1] = w4.y; wc[f][2] = w4.z; wc[f][3] = w4.w;
    }
    float bsum[4] = {0.f, 0.f, 0.f, 0.f};
#pragma unroll
    for (int f = 0; f < NFEAT; ++f) {
        const float4 b4 = *reinterpret_cast<const float4*>(bias + f * HID + h0);
        bsum[0] += b4.x; bsum[1] += b4.y; bsum[2] += b4.z; bsum[3] += b4.w;
    }
    const float4 g4   = *reinterpret_cast<const float4*>(gamma + h0);
    const float4 be4  = *reinterpret_cast<const float4*>(beta  + h0);
    const float4 on4  = *reinterpret_cast<const float4*>(fon   + h0);
    const float4 off4 = *reinterpret_cast<const float4*>(foff  + h0);
    const float gg[4]  = {g4.x,  g4.y,  g4.z,  g4.w};
    const float bb[4]  = {be4.x, be4.y, be4.z, be4.w};
    const float on[4]  = {on4.x, on4.y, on4.z, on4.w};
    const float offv[4]= {off4.x,off4.y,off4.z,off4.w};

    for (int t = gwave; t < ntokens; t += nwaves) {
        const int s = t & (SLEN - 1);

        // x[t, 0..7] — all lanes read the same 32B (cache broadcast)
        const float4 x0 = *reinterpret_cast<const float4*>(x + (size_t)t * NFEAT);
        const float4 x1 = *reinterpret_cast<const float4*>(x + (size_t)t * NFEAT + 4);
        const float xs[NFEAT] = {x0.x, x0.y, x0.z, x0.w, x1.x, x1.y, x1.z, x1.w};

        float v[4] = {bsum[0], bsum[1], bsum[2], bsum[3]};
#pragma unroll
        for (int f = 0; f < NFEAT; ++f) {
            const float xf = xs[f];
#pragma unroll
            for (int j = 0; j < 4; ++j) v[j] = fmaf(xf, wc[f][j], v[j]);
        }

        // index embedding (L2-resident, coalesced float4)
        const float4 e4 = *reinterpret_cast<const float4*>(ie + (size_t)s * HID + h0);
        v[0] += e4.x; v[1] += e4.y; v[2] += e4.z; v[3] += e4.w;

        // mask bias — wave-uniform value, scalar branch
        const int m = mask[t];
        if (m == 1) {
#pragma unroll
            for (int j = 0; j < 4; ++j) v[j] += on[j];
        } else if (m == 2) {
#pragma unroll
            for (int j = 0; j < 4; ++j) v[j] += offv[j];
        }

        // LayerNorm over H=256: wave-wide reduce of (sum, sumsq)
        float s1 = v[0] + v[1] + v[2] + v[3];
        float s2 = v[0]*v[0] + v[1]*v[1] + v[2]*v[2] + v[3]*v[3];
#pragma unroll
        for (int o = 32; o > 0; o >>= 1) {
            s1 += __shfl_xor(s1, o, 64);
            s2 += __shfl_xor(s2, o, 64);
        }
        const float mu   = s1 * (1.0f / HID);
        const float var  = s2 * (1.0f / HID) - mu * mu;
        const float rstd = rsqrtf(var + 1e-5f);

        float4 o4;
        o4.x = (v[0] - mu) * rstd * gg[0] + bb[0];
        o4.y = (v[1] - mu) * rstd * gg[1] + bb[1];
        o4.z = (v[2] - mu) * rstd * gg[2] + bb[2];
        o4.w = (v[3] - mu) * rstd * gg[3] + bb[3];
        *reinterpret_cast<float4*>(out + (size_t)t * HID + h0) = o4;
    }
}

extern "C" void kernel_launch(void* const* d_in, const int* in_sizes, int n_in,
                              void* d_out, int out_size, void* d_ws, size_t ws_size,
                              hipStream_t stream) {
    const float* x     = (const float*)d_in[0];
    const int*   mask  = (const int*)  d_in[1];
    const float* W     = (const float*)d_in[2];
    const float* bias  = (const float*)d_in[3];
    const float* ie    = (const float*)d_in[4];
    const float* fon   = (const float*)d_in[5];
    const float* foff  = (const float*)d_in[6];
    const float* gamma = (const float*)d_in[7];
    const float* beta  = (const float*)d_in[8];
    float* out = (float*)d_out;

    const int ntokens = in_sizes[0] / NFEAT;  // B*S = 262144

    const int block = 256;                 // 4 waves -> 4 tokens per block pass
    const int grid  = 2048;                // 8 blocks/CU, grid-stride over tokens

    stab_embed_ln_kernel<<<grid, block, 0, stream>>>(
        x, mask, W, bias, ie, fon, foff, gamma, beta, out, ntokens);
}

// Round 3
// 327.719 us; speedup vs baseline: 1.0361x; 1.0361x over previous
//
#include <hip/hip_runtime.h>

#define HID 256
#define NFEAT 8
#define SLEN 2048

// ---------------- P0: base2[s][h] = sum_f bias[f][h] + ie[s][h] ----------------
__global__ __launch_bounds__(256) void p0_base_kernel(
    const float* __restrict__ bias,   // [F,H]
    const float* __restrict__ ie,     // [S,H]
    float* __restrict__ base2,        // [S,H]
    int total4)                       // S*H/4
{
    const int idx = blockIdx.x * blockDim.x + threadIdx.x;
    if (idx >= total4) return;
    const int h0 = (idx & (HID / 4 - 1)) << 2;
    float4 r = *reinterpret_cast<const float4*>(ie + (size_t)idx * 4);
#pragma unroll
    for (int f = 0; f < NFEAT; ++f) {
        const float4 b4 = *reinterpret_cast<const float4*>(bias + f * HID + h0);
        r.x += b4.x; r.y += b4.y; r.z += b4.z; r.w += b4.w;
    }
    *reinterpret_cast<float4*>(base2 + (size_t)idx * 4) = r;
}

// ---------------- A: per-token (mu, rstd), one thread per token ----------------
// Wave layout: 2 waves per s-value; lane l of half q handles batch b = q*64+l,
// token t = b*SLEN + s.  W/base2/fon/foff loads are wave-uniform (L1 broadcast);
// x/mask are per-lane.  No cross-lane communication.
__global__ __launch_bounds__(256, 4) void a_stats_kernel(
    const float* __restrict__ x,      // [B,S,F]
    const int*   __restrict__ mask,   // [B,S]
    const float* __restrict__ W,      // [F,H]
    const float* __restrict__ base2,  // [S,H]
    const float* __restrict__ fon,    // [H]
    const float* __restrict__ foff,   // [H]
    float2* __restrict__ musig,       // [B*S]
    int Bdim, int ntokens)
{
    const int lane  = threadIdx.x & 63;
    const int gwave = (blockIdx.x * blockDim.x + threadIdx.x) >> 6;
    const int s     = gwave >> 1;          // 2 waves per s
    const int b     = ((gwave & 1) << 6) + lane;
    if (b >= Bdim) return;
    const int t = b * SLEN + s;

    const float4 x0 = *reinterpret_cast<const float4*>(x + (size_t)t * NFEAT);
    const float4 x1 = *reinterpret_cast<const float4*>(x + (size_t)t * NFEAT + 4);
    const float xs[NFEAT] = {x0.x, x0.y, x0.z, x0.w, x1.x, x1.y, x1.z, x1.w};
    const int m = mask[t];
    const float fm1 = (m == 1) ? 1.0f : 0.0f;
    const float fm2 = (m == 2) ? 1.0f : 0.0f;

    float s1 = 0.0f, s2 = 0.0f;
    for (int h0 = 0; h0 < HID; h0 += 4) {
        float4 acc = *reinterpret_cast<const float4*>(base2 + s * HID + h0);
#pragma unroll
        for (int f = 0; f < NFEAT; ++f) {
            const float4 w4 = *reinterpret_cast<const float4*>(W + f * HID + h0);
            acc.x = fmaf(xs[f], w4.x, acc.x);
            acc.y = fmaf(xs[f], w4.y, acc.y);
            acc.z = fmaf(xs[f], w4.z, acc.z);
            acc.w = fmaf(xs[f], w4.w, acc.w);
        }
        const float4 on4 = *reinterpret_cast<const float4*>(fon  + h0);
        const float4 of4 = *reinterpret_cast<const float4*>(foff + h0);
        acc.x += fm1 * on4.x + fm2 * of4.x;
        acc.y += fm1 * on4.y + fm2 * of4.y;
        acc.z += fm1 * on4.z + fm2 * of4.z;
        acc.w += fm1 * on4.w + fm2 * of4.w;
        s1 += acc.x + acc.y + acc.z + acc.w;
        s2 = fmaf(acc.x, acc.x, s2);
        s2 = fmaf(acc.y, acc.y, s2);
        s2 = fmaf(acc.z, acc.z, s2);
        s2 = fmaf(acc.w, acc.w, s2);
    }
    const float mu   = s1 * (1.0f / HID);
    const float var  = s2 * (1.0f / HID) - mu * mu;
    const float rstd = rsqrtf(var + 1e-5f);
    musig[t] = make_float2(mu, rstd);
}

// ---------------- B: recompute h, normalize with (mu,rstd), store -------------
__global__ __launch_bounds__(256, 4) void b_apply_kernel(
    const float* __restrict__ x,      // [B,S,F]
    const int*   __restrict__ mask,   // [B,S]
    const float* __restrict__ W,      // [F,H]
    const float* __restrict__ base2,  // [S,H]
    const float* __restrict__ fon,    // [H]
    const float* __restrict__ foff,   // [H]
    const float* __restrict__ gamma,  // [H]
    const float* __restrict__ beta,   // [H]
    const float2* __restrict__ musig, // [B*S]
    float* __restrict__ out,          // [B,S,H]
    int ntokens)
{
    const int lane = threadIdx.x & 63;
    const int wavesPerBlock = blockDim.x >> 6;
    const int gwave = blockIdx.x * wavesPerBlock + (threadIdx.x >> 6);
    const int nwaves = gridDim.x * wavesPerBlock;
    const int h0 = lane << 2;

    // hoisted per-lane invariants: W columns, gamma, beta  (~44 VGPRs)
    float wc[NFEAT][4];
#pragma unroll
    for (int f = 0; f < NFEAT; ++f) {
        const float4 w4 = *reinterpret_cast<const float4*>(W + f * HID + h0);
        wc[f][0] = w4.x; wc[f][1] = w4.y; wc[f][2] = w4.z; wc[f][3] = w4.w;
    }
    const float4 g4  = *reinterpret_cast<const float4*>(gamma + h0);
    const float4 be4 = *reinterpret_cast<const float4*>(beta  + h0);

    for (int t = gwave; t < ntokens; t += nwaves) {
        const int s = t & (SLEN - 1);

        // independent loads issued up front: stats, base row, x, mask
        const float2 ms = musig[t];
        float4 acc = *reinterpret_cast<const float4*>(base2 + (size_t)s * HID + h0);
        const float4 x0 = *reinterpret_cast<const float4*>(x + (size_t)t * NFEAT);
        const float4 x1 = *reinterpret_cast<const float4*>(x + (size_t)t * NFEAT + 4);
        const int m = mask[t];

        if (m == 1) {            // wave-uniform branch, L1-hit broadcast loads
            const float4 on4 = *reinterpret_cast<const float4*>(fon + h0);
            acc.x += on4.x; acc.y += on4.y; acc.z += on4.z; acc.w += on4.w;
        } else if (m == 2) {
            const float4 of4 = *reinterpret_cast<const float4*>(foff + h0);
            acc.x += of4.x; acc.y += of4.y; acc.z += of4.z; acc.w += of4.w;
        }

        const float xs[NFEAT] = {x0.x, x0.y, x0.z, x0.w, x1.x, x1.y, x1.z, x1.w};
#pragma unroll
        for (int f = 0; f < NFEAT; ++f) {
            acc.x = fmaf(xs[f], wc[f][0], acc.x);
            acc.y = fmaf(xs[f], wc[f][1], acc.y);
            acc.z = fmaf(xs[f], wc[f][2], acc.z);
            acc.w = fmaf(xs[f], wc[f][3], acc.w);
        }

        float4 o4;
        o4.x = (acc.x - ms.x) * ms.y * g4.x + be4.x;
        o4.y = (acc.y - ms.x) * ms.y * g4.y + be4.y;
        o4.z = (acc.z - ms.x) * ms.y * g4.z + be4.z;
        o4.w = (acc.w - ms.x) * ms.y * g4.w + be4.w;
        *reinterpret_cast<float4*>(out + (size_t)t * HID + h0) = o4;
    }
}

extern "C" void kernel_launch(void* const* d_in, const int* in_sizes, int n_in,
                              void* d_out, int out_size, void* d_ws, size_t ws_size,
                              hipStream_t stream) {
    const float* x     = (const float*)d_in[0];
    const int*   mask  = (const int*)  d_in[1];
    const float* W     = (const float*)d_in[2];
    const float* bias  = (const float*)d_in[3];
    const float* ie    = (const float*)d_in[4];
    const float* fon   = (const float*)d_in[5];
    const float* foff  = (const float*)d_in[6];
    const float* gamma = (const float*)d_in[7];
    const float* beta  = (const float*)d_in[8];
    float* out = (float*)d_out;

    const int ntokens = in_sizes[0] / NFEAT;   // B*S
    const int Bdim    = ntokens / SLEN;        // 128

    // workspace layout: base2 [S*H] floats, then musig [ntokens] float2
    float*  base2 = (float*)d_ws;
    float2* musig = (float2*)((char*)d_ws + (size_t)SLEN * HID * sizeof(float));

    // P0: build base2 (S*H/4 threads)
    {
        const int total4 = SLEN * HID / 4;
        p0_base_kernel<<<(total4 + 255) / 256, 256, 0, stream>>>(bias, ie, base2, total4);
    }
    // A: per-token stats. 2 waves per s  ->  2*SLEN waves total.
    {
        const int waves = 2 * SLEN;
        a_stats_kernel<<<(waves * 64) / 256, 256, 0, stream>>>(
            x, mask, W, base2, fon, foff, musig, Bdim, ntokens);
    }
    // B: streaming apply. 2048 blocks, grid-stride, 1 token per wave pass.
    {
        b_apply_kernel<<<2048, 256, 0, stream>>>(
            x, mask, W, base2, fon, foff, gamma, beta, musig, out, ntokens);
    }
}